// Round 3
// baseline (546.067 us; speedup 1.0000x reference)
//
#include <hip/hip_runtime.h>
#include <hip/hip_bf16.h>
#include <math.h>

// Problem constants (from reference)
#define NNODES 10000
#define MPAD   10112    // 79 * 128
#define EDGES  160000
#define EPLUS  170000   // EDGES + NNODES self-loops
#define FIN    512
#define HEADS8 8
#define CH     64
#define HC     512      // HEADS8*CH
#define NG     64       // graphs
#define NCLS   64
#define NPART  64       // bn partial blocks

typedef _Float16 f16x8 __attribute__((ext_vector_type(8)));
typedef _Float16 f16x4 __attribute__((ext_vector_type(4)));
typedef float    f32x4 __attribute__((ext_vector_type(4)));

#define GLD_LDS16(g, l)                                                        \
    __builtin_amdgcn_global_load_lds(                                          \
        (const __attribute__((address_space(1))) void*)(g),                    \
        (__attribute__((address_space(3))) void*)(l), 16, 0, 0)

// ---------------------------------------------------------------------------
// CSR build: histogram of dst, exclusive scan, scatter src indices
// ---------------------------------------------------------------------------
__global__ void count_deg(const int* __restrict__ ei, int* __restrict__ deg)
{
    int e = blockIdx.x * blockDim.x + threadIdx.x;
    if (e >= EPLUS) return;
    int dst = (e < EDGES) ? ei[EDGES + e] : (e - EDGES);
    atomicAdd(&deg[dst], 1);
}

__global__ void exscan_deg(const int* __restrict__ deg, int* __restrict__ off)
{
    __shared__ int partial[256];
    const int tid = threadIdx.x;
    const int chunk = (NNODES + 255) / 256; // 40
    int begin = tid * chunk;
    int end   = begin + chunk; if (end > NNODES) end = NNODES;
    if (begin > NNODES) begin = NNODES;
    int s = 0;
    for (int i = begin; i < end; ++i) s += deg[i];
    partial[tid] = s;
    __syncthreads();
    for (int o = 1; o < 256; o <<= 1) {
        int v = (tid >= o) ? partial[tid - o] : 0;
        __syncthreads();
        partial[tid] += v;
        __syncthreads();
    }
    int run = (tid > 0) ? partial[tid - 1] : 0;  // exclusive prefix
    for (int i = begin; i < end; ++i) { off[i] = run; run += deg[i]; }
    if (tid == 255) off[NNODES] = run; // == EPLUS
}

__global__ void scatter_edges(const int* __restrict__ ei, int* __restrict__ cursor,
                              int* __restrict__ csr)
{
    int e = blockIdx.x * blockDim.x + threadIdx.x;
    if (e >= EPLUS) return;
    int srcN, dstN;
    if (e < EDGES) { srcN = ei[e]; dstN = ei[EDGES + e]; }
    else           { srcN = dstN = e - EDGES; }
    int pos = atomicAdd(&cursor[dstN], 1);
    csr[pos] = srcN;
}

// ---------------------------------------------------------------------------
// Graph boundary offsets from sorted batch: goff[g] = first node with batch>=g
// ---------------------------------------------------------------------------
__global__ void graph_offsets(const int* __restrict__ batch, int* __restrict__ goff)
{
    int i = blockIdx.x * 256 + threadIdx.x;
    if (i >= NNODES) return;
    int b = batch[i];
    int bprev = (i == 0) ? -1 : batch[i - 1];
    for (int g = bprev + 1; g <= b; ++g) goff[g] = i;
    if (i == NNODES - 1)
        for (int g = b + 1; g <= NG; ++g) goff[g] = NNODES;
}

// ---------------------------------------------------------------------------
// fp32 -> fp16 conversions
// ---------------------------------------------------------------------------
__global__ void conv_f32_f16(const float* __restrict__ src,
                             _Float16* __restrict__ dst, int n4)
{
    int i = blockIdx.x * 256 + threadIdx.x;
    if (i >= n4) return;
    float4 v = ((const float4*)src)[i];
    f16x4 o;
    o[0] = (_Float16)v.x; o[1] = (_Float16)v.y;
    o[2] = (_Float16)v.z; o[3] = (_Float16)v.w;
    ((f16x4*)dst)[i] = o;
}

// W [512 x 512] row-major (K x N)  ->  Wt [N x K] fp16
__global__ void transp_f32_f16(const float* __restrict__ W,
                               _Float16* __restrict__ Wt)
{
    __shared__ float t[32][33];
    int bx = blockIdx.x * 32, by = blockIdx.y * 32;
    int tx = threadIdx.x, ty = threadIdx.y;   // 32 x 8
    #pragma unroll
    for (int i = 0; i < 32; i += 8)
        t[ty + i][tx] = W[(size_t)(by + ty + i) * 512 + bx + tx];
    __syncthreads();
    #pragma unroll
    for (int i = 0; i < 32; i += 8)
        Wt[(size_t)(bx + ty + i) * 512 + by + tx] = (_Float16)t[tx][ty + i];
}

// ---------------------------------------------------------------------------
// fp16 MFMA GEMM: C[M,N] = A16[M,K] @ Bt16[N,K]^T (+bias)
// ---------------------------------------------------------------------------
__global__ __launch_bounds__(256) void gemm_f16_mfma(
    const _Float16* __restrict__ A16, const _Float16* __restrict__ Bt16,
    const float* __restrict__ bias, float* __restrict__ Cp,
    _Float16* __restrict__ C16, int M, int Nn, int K)
{
    __shared__ _Float16 As[128 * 32] __attribute__((aligned(16)));
    __shared__ _Float16 Bs[128 * 32] __attribute__((aligned(16)));
    const int tid  = threadIdx.x;
    const int wave = tid >> 6;
    const int lane = tid & 63;
    const int row0 = blockIdx.y * 128;
    const int col0 = blockIdx.x * 128;
    const int wy = wave >> 1, wx = wave & 1;

    const int lrow = lane >> 2;
    const int lk   = (lane & 3) * 8;

    f32x4 acc[4][4] = {};

    for (int k0 = 0; k0 < K; k0 += 32) {
        if (k0) __syncthreads();
        #pragma unroll
        for (int r = 0; r < 2; ++r) {
            const int chunk = r * 4 + wave;
            const int trow  = chunk * 16 + lrow;
            const _Float16* ga = A16 + (size_t)(row0 + trow) * K + k0 + lk;
            GLD_LDS16(ga, &As[chunk * 512]);
            const _Float16* gb = Bt16 + (size_t)(col0 + trow) * K + k0 + lk;
            GLD_LDS16(gb, &Bs[chunk * 512]);
        }
        __syncthreads();

        const int quad = lane >> 4;
        const int l16  = lane & 15;
        f16x8 af[4], bf[4];
        #pragma unroll
        for (int m = 0; m < 4; ++m)
            af[m] = *(const f16x8*)&As[(wy * 64 + m * 16 + l16) * 32 + quad * 8];
        #pragma unroll
        for (int n = 0; n < 4; ++n)
            bf[n] = *(const f16x8*)&Bs[(wx * 64 + n * 16 + l16) * 32 + quad * 8];
        #pragma unroll
        for (int m = 0; m < 4; ++m)
            #pragma unroll
            for (int n = 0; n < 4; ++n)
                acc[m][n] = __builtin_amdgcn_mfma_f32_16x16x32_f16(
                    af[m], bf[n], acc[m][n], 0, 0, 0);
    }

    const int quad = lane >> 4;
    const int l16  = lane & 15;
    #pragma unroll
    for (int m = 0; m < 4; ++m) {
        #pragma unroll
        for (int n = 0; n < 4; ++n) {
            const int col = col0 + wx * 64 + n * 16 + l16;
            const float bv = bias ? bias[col] : 0.0f;
            #pragma unroll
            for (int r = 0; r < 4; ++r) {
                const int row = row0 + wy * 64 + m * 16 + quad * 4 + r;
                if (row < M) {
                    float v = acc[m][n][r] + bv;
                    if (Cp)  Cp[(size_t)row * Nn + col] = v;
                    if (C16) C16[(size_t)row * Nn + col] = (_Float16)v;
                }
            }
        }
    }
}

// ---------------------------------------------------------------------------
// Tiled fp32 GEMM (layer 3, N=64)
// ---------------------------------------------------------------------------
__global__ __launch_bounds__(256) void gemm_bias_f32(
    const float* __restrict__ A, const float* __restrict__ B,
    const float* __restrict__ bias, float* __restrict__ Cm,
    int M, int Nn, int K)
{
    __shared__ float As[16][68];
    __shared__ float Bs[16][68];
    const int tid  = threadIdx.x;
    const int row0 = blockIdx.y * 64;
    const int col0 = blockIdx.x * 64;
    const int tx = tid & 15, ty = tid >> 4;
    const int am = tid >> 2,  ak = (tid & 3) << 2;
    const int bk = tid >> 4,  bc = (tid & 15) << 2;
    float acc[4][4] = {};
    for (int k0 = 0; k0 < K; k0 += 16) {
        float4 av;
        if (row0 + am < M)
            av = *(const float4*)(A + (size_t)(row0 + am) * K + k0 + ak);
        else
            av = make_float4(0.f, 0.f, 0.f, 0.f);
        As[ak + 0][am] = av.x; As[ak + 1][am] = av.y;
        As[ak + 2][am] = av.z; As[ak + 3][am] = av.w;
        float4 bv = *(const float4*)(B + (size_t)(k0 + bk) * Nn + col0 + bc);
        Bs[bk][bc + 0] = bv.x; Bs[bk][bc + 1] = bv.y;
        Bs[bk][bc + 2] = bv.z; Bs[bk][bc + 3] = bv.w;
        __syncthreads();
        #pragma unroll
        for (int kk = 0; kk < 16; ++kk) {
            float a0 = As[kk][ty * 4 + 0], a1 = As[kk][ty * 4 + 1];
            float a2 = As[kk][ty * 4 + 2], a3 = As[kk][ty * 4 + 3];
            float b0 = Bs[kk][tx * 4 + 0], b1 = Bs[kk][tx * 4 + 1];
            float b2 = Bs[kk][tx * 4 + 2], b3 = Bs[kk][tx * 4 + 3];
            acc[0][0] = fmaf(a0, b0, acc[0][0]); acc[0][1] = fmaf(a0, b1, acc[0][1]);
            acc[0][2] = fmaf(a0, b2, acc[0][2]); acc[0][3] = fmaf(a0, b3, acc[0][3]);
            acc[1][0] = fmaf(a1, b0, acc[1][0]); acc[1][1] = fmaf(a1, b1, acc[1][1]);
            acc[1][2] = fmaf(a1, b2, acc[1][2]); acc[1][3] = fmaf(a1, b3, acc[1][3]);
            acc[2][0] = fmaf(a2, b0, acc[2][0]); acc[2][1] = fmaf(a2, b1, acc[2][1]);
            acc[2][2] = fmaf(a2, b2, acc[2][2]); acc[2][3] = fmaf(a2, b3, acc[2][3]);
            acc[3][0] = fmaf(a3, b0, acc[3][0]); acc[3][1] = fmaf(a3, b1, acc[3][1]);
            acc[3][2] = fmaf(a3, b2, acc[3][2]); acc[3][3] = fmaf(a3, b3, acc[3][3]);
        }
        __syncthreads();
    }
    #pragma unroll
    for (int i = 0; i < 4; ++i) {
        int r = row0 + ty * 4 + i;
        if (r < M) {
            #pragma unroll
            for (int j = 0; j < 4; ++j) {
                int c = col0 + tx * 4 + j;
                float v = acc[i][j];
                if (bias) v += bias[c];
                Cm[(size_t)r * Nn + c] = v;
            }
        }
    }
}

// ---------------------------------------------------------------------------
// Attention scores
// ---------------------------------------------------------------------------
template <int NH, typename TH>
__global__ __launch_bounds__(64) void compute_scores(
    const TH* __restrict__ Hf, const float* __restrict__ a_s,
    const float* __restrict__ a_d, float* __restrict__ ssrc,
    float* __restrict__ sdst)
{
    const int node = blockIdx.x;
    const int lane = threadIdx.x;
    const TH* hp = Hf + (size_t)node * (NH * 64) + lane;
    #pragma unroll
    for (int h = 0; h < NH; ++h) {
        float v  = (float)hp[h * 64];
        float vs = v * a_s[h * 64 + lane];
        float vd = v * a_d[h * 64 + lane];
        #pragma unroll
        for (int o = 32; o; o >>= 1) {
            vs += __shfl_down(vs, o);
            vd += __shfl_down(vd, o);
        }
        if (lane == 0) {
            ssrc[node * NH + h] = vs;
            sdst[node * NH + h] = vd;
        }
    }
}

// ---------------------------------------------------------------------------
// Segment-softmax aggregation, one wave per dst node, lane = channel.
// ---------------------------------------------------------------------------
template <int NH, typename TH>
__global__ __launch_bounds__(64) void gat_aggregate(
    const TH* __restrict__ Hf, const float* __restrict__ ssrc,
    const float* __restrict__ sdst, const int* __restrict__ off,
    const int* __restrict__ csr, const float* __restrict__ bias,
    float* __restrict__ out)
{
    const int n    = blockIdx.x;
    const int lane = threadIdx.x;
    const int e0 = off[n], e1 = off[n + 1];

    float sd[NH];
    #pragma unroll
    for (int h = 0; h < NH; ++h) sd[h] = sdst[n * NH + h];

    float mx[NH];
    #pragma unroll
    for (int h = 0; h < NH; ++h) mx[h] = -1e30f;
    for (int e = e0 + lane; e < e1; e += 64) {
        int s = csr[e];
        #pragma unroll
        for (int h = 0; h < NH; ++h) {
            float l = ssrc[s * NH + h] + sd[h];
            l = (l > 0.f) ? l : 0.2f * l;
            mx[h] = fmaxf(mx[h], l);
        }
    }
    #pragma unroll
    for (int h = 0; h < NH; ++h)
        #pragma unroll
        for (int o = 1; o < 64; o <<= 1)
            mx[h] = fmaxf(mx[h], __shfl_xor(mx[h], o));

    __shared__ float exL[64][NH];
    __shared__ int   srcL[64];
    float acc[NH]  = {};
    float ssum[NH] = {};
    for (int base = e0; base < e1; base += 64) {
        int cnt = e1 - base; if (cnt > 64) cnt = 64;
        if (lane < cnt) {
            int s = csr[base + lane];
            srcL[lane] = s;
            #pragma unroll
            for (int h = 0; h < NH; ++h) {
                float l = ssrc[s * NH + h] + sd[h];
                l = (l > 0.f) ? l : 0.2f * l;
                float ex = expf(l - mx[h]);
                exL[lane][h] = ex;
                ssum[h] += ex;
            }
        }
        __syncthreads();
        for (int j = 0; j < cnt; ++j) {
            const int s = srcL[j];
            const TH* hp = Hf + (size_t)s * (NH * 64) + lane;
            #pragma unroll
            for (int h = 0; h < NH; ++h)
                acc[h] = fmaf(exL[j][h], (float)hp[h * 64], acc[h]);
        }
        __syncthreads();
    }
    #pragma unroll
    for (int h = 0; h < NH; ++h)
        #pragma unroll
        for (int o = 1; o < 64; o <<= 1)
            ssum[h] += __shfl_xor(ssum[h], o);

    #pragma unroll
    for (int h = 0; h < NH; ++h)
        out[(size_t)n * (NH * 64) + h * 64 + lane] =
            acc[h] / (ssum[h] + 1e-16f) + bias[h * 64 + lane];
}

// ---------------------------------------------------------------------------
// BatchNorm: partial column sums (no atomics), finalize reduces partials
// ---------------------------------------------------------------------------
__global__ void bn_stats_part(const float* __restrict__ x,
                              float* __restrict__ psum, float* __restrict__ psq,
                              int rows, int cols)
{
    const int c   = threadIdx.x;   // blockDim.x == cols
    const int blk = blockIdx.x;    // NPART blocks
    float s = 0.f, sq = 0.f;
    for (int r = blk; r < rows; r += NPART) {
        float v = x[(size_t)r * cols + c];
        s += v; sq += v * v;
    }
    psum[(size_t)blk * cols + c] = s;
    psq [(size_t)blk * cols + c] = sq;
}

__global__ void bn_finalize(const float* __restrict__ psum,
                            const float* __restrict__ psq,
                            float* __restrict__ mean, float* __restrict__ invstd,
                            int cols, float invN)
{
    int c = blockIdx.x * blockDim.x + threadIdx.x;
    if (c >= cols) return;
    float s = 0.f, sq = 0.f;
    for (int p = 0; p < NPART; ++p) {
        s  += psum[(size_t)p * cols + c];
        sq += psq [(size_t)p * cols + c];
    }
    float mu  = s * invN;
    float var = sq * invN - mu * mu;
    mean[c]   = mu;
    invstd[c] = 1.0f / sqrtf(var + 1e-5f);
}

// BN apply + ELU + residual; optionally emits fp16 copy for next fp16 GEMM
__global__ void bn_apply(float* __restrict__ x, const float* __restrict__ res,
                         const float* __restrict__ mean, const float* __restrict__ invstd,
                         const float* __restrict__ g, const float* __restrict__ be,
                         _Float16* __restrict__ out16,
                         size_t total, int colmask, int do_elu)
{
    size_t i = (size_t)blockIdx.x * blockDim.x + threadIdx.x;
    if (i >= total) return;
    int c = (int)(i & (size_t)colmask);
    float v = g[c] * (x[i] - mean[c]) * invstd[c] + be[c];
    if (do_elu) v = (v > 0.f) ? v : expm1f(v);
    if (res) v += res[i];
    x[i] = v;
    if (out16) out16[i] = (_Float16)v;
}

// ---------------------------------------------------------------------------
// Global mean pool (segment-based, batch sorted -> contiguous ranges)
// One block per graph; lane = channel; 4 waves stride rows; LDS reduce.
// Writes the MEAN directly.
// ---------------------------------------------------------------------------
__global__ __launch_bounds__(256) void pool_mean(
    const float* __restrict__ x, const int* __restrict__ goff,
    float* __restrict__ means)
{
    const int g    = blockIdx.x;
    const int lane = threadIdx.x & 63;   // channel
    const int wave = threadIdx.x >> 6;   // 0..3
    const int r0 = goff[g], r1 = goff[g + 1];
    float s = 0.f;
    for (int r = r0 + wave; r < r1; r += 4)
        s += x[(size_t)r * CH + lane];
    __shared__ float red[4][CH];
    red[wave][lane] = s;
    __syncthreads();
    if (wave == 0) {
        float tot = red[0][lane] + red[1][lane] + red[2][lane] + red[3][lane];
        float cnt = (float)(r1 - r0);
        means[g * CH + lane] = tot / fmaxf(cnt, 1.0f);
    }
}

__global__ __launch_bounds__(64) void final_linear(
    const float* __restrict__ means, const float* __restrict__ W,
    const float* __restrict__ b, float* __restrict__ out)
{
    const int g = blockIdx.x;
    const int j = threadIdx.x;
    float acc = b[j];
    for (int c = 0; c < CH; ++c)
        acc = fmaf(means[g * CH + c], W[c * NCLS + j], acc);
    out[g * NCLS + j] = acc;
}

// ---------------------------------------------------------------------------
// Host launcher
// ---------------------------------------------------------------------------
extern "C" void kernel_launch(void* const* d_in, const int* in_sizes, int n_in,
                              void* d_out, int out_size, void* d_ws, size_t ws_size,
                              hipStream_t stream)
{
    const float* x_in  = (const float*)d_in[0];
    const int*   ei    = (const int*)  d_in[1];
    const int*   batch = (const int*)  d_in[2];
    const float* enc_W = (const float*)d_in[3];
    const float* enc_b = (const float*)d_in[4];
    const float* W1  = (const float*)d_in[5];
    const float* as1 = (const float*)d_in[6];
    const float* ad1 = (const float*)d_in[7];
    const float* b1  = (const float*)d_in[8];
    const float* g1  = (const float*)d_in[9];
    const float* be1 = (const float*)d_in[10];
    const float* W2  = (const float*)d_in[11];
    const float* as2 = (const float*)d_in[12];
    const float* ad2 = (const float*)d_in[13];
    const float* b2  = (const float*)d_in[14];
    const float* g2  = (const float*)d_in[15];
    const float* be2 = (const float*)d_in[16];
    const float* W3  = (const float*)d_in[17];
    const float* as3 = (const float*)d_in[18];
    const float* ad3 = (const float*)d_in[19];
    const float* b3  = (const float*)d_in[20];
    const float* g3  = (const float*)d_in[21];
    const float* be3 = (const float*)d_in[22];
    const float* linW = (const float*)d_in[23];
    const float* linb = (const float*)d_in[24];
    float* out = (float*)d_out;

    char* ws = (char*)d_ws;
    size_t off_b = 0;
    auto alloc = [&](size_t bytes) -> void* {
        void* p = ws + off_b;
        off_b = (off_b + bytes + 255) & ~(size_t)255;
        return p;
    };
    float*    xA     = (float*)alloc((size_t)NNODES * HC * 4);
    float*    xC     = (float*)alloc((size_t)NNODES * HC * 4);
    _Float16* f16A   = (_Float16*)alloc((size_t)MPAD * HC * 2);
    _Float16* f16B   = (_Float16*)alloc((size_t)MPAD * HC * 2);
    _Float16* H16    = (_Float16*)alloc((size_t)NNODES * HC * 2);
    float*    h3f    = (float*)alloc((size_t)NNODES * CH * 4);
    float*    g3o    = (float*)alloc((size_t)NNODES * CH * 4);
    _Float16* encWt  = (_Float16*)alloc((size_t)HC * FIN * 2);
    _Float16* W1t    = (_Float16*)alloc((size_t)HC * HC * 2);
    _Float16* W2t    = (_Float16*)alloc((size_t)HC * HC * 2);
    float* ssrc   = (float*)alloc((size_t)NNODES * HEADS8 * 4);
    float* sdst   = (float*)alloc((size_t)NNODES * HEADS8 * 4);
    int*   deg    = (int*)  alloc((size_t)NNODES * 4);
    int*   offp   = (int*)  alloc((size_t)(NNODES + 1) * 4);
    int*   cursor = (int*)  alloc((size_t)NNODES * 4);
    int*   csr    = (int*)  alloc((size_t)EPLUS * 4);
    int*   goff   = (int*)  alloc((size_t)(NG + 1) * 4);
    float* psum   = (float*)alloc((size_t)NPART * HC * 4);
    float* psq    = (float*)alloc((size_t)NPART * HC * 4);
    float* meanb  = (float*)alloc(HC * 4);
    float* invstd = (float*)alloc(HC * 4);
    float* gmeans = (float*)alloc((size_t)NG * CH * 4);

    // ---- CSR build + graph offsets
    hipMemsetAsync(deg, 0, (size_t)NNODES * 4, stream);
    count_deg<<<(EPLUS + 255) / 256, 256, 0, stream>>>(ei, deg);
    exscan_deg<<<1, 256, 0, stream>>>(deg, offp);
    hipMemcpyAsync(cursor, offp, (size_t)NNODES * 4, hipMemcpyDeviceToDevice, stream);
    scatter_edges<<<(EPLUS + 255) / 256, 256, 0, stream>>>(ei, cursor, csr);
    graph_offsets<<<(NNODES + 255) / 256, 256, 0, stream>>>(batch, goff);

    // ---- fp16 conversions (input + transposed weights)
    {
        int n4 = NNODES * FIN / 4;
        conv_f32_f16<<<(n4 + 255) / 256, 256, 0, stream>>>(x_in, f16A, n4);
        dim3 tg(16, 16), tb(32, 8);
        transp_f32_f16<<<tg, tb, 0, stream>>>(enc_W, encWt);
        transp_f32_f16<<<tg, tb, 0, stream>>>(W1, W1t);
        transp_f32_f16<<<tg, tb, 0, stream>>>(W2, W2t);
    }

    const dim3 mfma_grid(HC / 128, MPAD / 128);
    const dim3 gemm_grid_c(CH / 64, (NNODES + 63) / 64);

    // ---- Encoder
    gemm_f16_mfma<<<mfma_grid, 256, 0, stream>>>(f16A, encWt, enc_b, xA, f16B,
                                                 NNODES, HC, FIN);

    // ---- GAT layer (fp16 H path)
    auto run_layer = [&](const _Float16* a16, const _Float16* wt,
                         const float* xin_res, float* gout, _Float16* out16,
                         const float* a_s, const float* a_d,
                         const float* bconv, const float* gg, const float* bb) {
        gemm_f16_mfma<<<mfma_grid, 256, 0, stream>>>(a16, wt, nullptr, nullptr,
                                                     H16, NNODES, HC, HC);
        compute_scores<HEADS8, _Float16><<<NNODES, 64, 0, stream>>>(
            H16, a_s, a_d, ssrc, sdst);
        gat_aggregate<HEADS8, _Float16><<<NNODES, 64, 0, stream>>>(
            H16, ssrc, sdst, offp, csr, bconv, gout);
        bn_stats_part<<<NPART, HC, 0, stream>>>(gout, psum, psq, NNODES, HC);
        bn_finalize<<<1, HC, 0, stream>>>(psum, psq, meanb, invstd, HC,
                                          1.0f / NNODES);
        size_t total = (size_t)NNODES * HC;
        bn_apply<<<(total + 255) / 256, 256, 0, stream>>>(
            gout, xin_res, meanb, invstd, gg, bb, out16, total, HC - 1, 1);
    };

    run_layer(f16B, W1t, xA, xC, f16A, as1, ad1, b1, g1, be1);
    run_layer(f16A, W2t, xC, xA, nullptr, as2, ad2, b2, g2, be2);

    // ---- Layer 3 (heads=1, C=64, fp32 GEMM)
    gemm_bias_f32<<<gemm_grid_c, 256, 0, stream>>>(xA, W3, nullptr, h3f,
                                                   NNODES, CH, HC);
    compute_scores<1, float><<<NNODES, 64, 0, stream>>>(h3f, as3, ad3, ssrc, sdst);
    gat_aggregate<1, float><<<NNODES, 64, 0, stream>>>(h3f, ssrc, sdst, offp,
                                                       csr, b3, g3o);
    bn_stats_part<<<NPART, CH, 0, stream>>>(g3o, psum, psq, NNODES, CH);
    bn_finalize<<<1, CH, 0, stream>>>(psum, psq, meanb, invstd, CH,
                                      1.0f / NNODES);
    {
        size_t total = (size_t)NNODES * CH;
        bn_apply<<<(total + 255) / 256, 256, 0, stream>>>(
            g3o, nullptr, meanb, invstd, g3, be3, nullptr, total, CH - 1, 0);
    }

    // ---- Global mean pool + final linear
    pool_mean<<<NG, 256, 0, stream>>>(g3o, goff, gmeans);
    final_linear<<<NG, 64, 0, stream>>>(gmeans, linW, linb, out);
}

// Round 4
// 482.443 us; speedup vs baseline: 1.1319x; 1.1319x over previous
//
#include <hip/hip_runtime.h>
#include <hip/hip_bf16.h>
#include <math.h>

// Problem constants (from reference)
#define NNODES 10000
#define MPAD   10112    // 79 * 128
#define EDGES  160000
#define EPLUS  170000   // EDGES + NNODES self-loops
#define FIN    512
#define HEADS8 8
#define CH     64
#define HC     512      // HEADS8*CH
#define NG     64       // graphs
#define NCLS   64
#define NPART  128      // bn partial blocks

typedef _Float16 f16x8 __attribute__((ext_vector_type(8)));
typedef _Float16 f16x4 __attribute__((ext_vector_type(4)));
typedef float    f32x4 __attribute__((ext_vector_type(4)));

#define GLD_LDS16(g, l)                                                        \
    __builtin_amdgcn_global_load_lds(                                          \
        (const __attribute__((address_space(1))) void*)(g),                    \
        (__attribute__((address_space(3))) void*)(l), 16, 0, 0)

// ---------------------------------------------------------------------------
// CSR build: histogram of dst (+ graph offsets fused), scan, scatter
// ---------------------------------------------------------------------------
__global__ void count_deg_goff(const int* __restrict__ ei, int* __restrict__ deg,
                               const int* __restrict__ batch, int* __restrict__ goff)
{
    int e = blockIdx.x * blockDim.x + threadIdx.x;
    if (e < NNODES) {  // graph boundary detection on sorted batch
        int b = batch[e];
        int bprev = (e == 0) ? -1 : batch[e - 1];
        for (int g = bprev + 1; g <= b; ++g) goff[g] = e;
        if (e == NNODES - 1)
            for (int g = b + 1; g <= NG; ++g) goff[g] = NNODES;
    }
    if (e >= EPLUS) return;
    int dst = (e < EDGES) ? ei[EDGES + e] : (e - EDGES);
    atomicAdd(&deg[dst], 1);
}

__global__ void exscan_deg(const int* __restrict__ deg, int* __restrict__ off,
                           int* __restrict__ cursor)
{
    __shared__ int partial[256];
    const int tid = threadIdx.x;
    const int chunk = (NNODES + 255) / 256; // 40
    int begin = tid * chunk;
    int end   = begin + chunk; if (end > NNODES) end = NNODES;
    if (begin > NNODES) begin = NNODES;
    int s = 0;
    for (int i = begin; i < end; ++i) s += deg[i];
    partial[tid] = s;
    __syncthreads();
    for (int o = 1; o < 256; o <<= 1) {
        int v = (tid >= o) ? partial[tid - o] : 0;
        __syncthreads();
        partial[tid] += v;
        __syncthreads();
    }
    int run = (tid > 0) ? partial[tid - 1] : 0;  // exclusive prefix
    for (int i = begin; i < end; ++i) {
        off[i] = run; cursor[i] = run; run += deg[i];
    }
    if (tid == 255) off[NNODES] = run; // == EPLUS
}

__global__ void scatter_edges(const int* __restrict__ ei, int* __restrict__ cursor,
                              int* __restrict__ csr)
{
    int e = blockIdx.x * blockDim.x + threadIdx.x;
    if (e >= EPLUS) return;
    int srcN, dstN;
    if (e < EDGES) { srcN = ei[e]; dstN = ei[EDGES + e]; }
    else           { srcN = dstN = e - EDGES; }
    int pos = atomicAdd(&cursor[dstN], 1);
    csr[pos] = srcN;
}

// ---------------------------------------------------------------------------
// fp32 -> fp16 conversions
// ---------------------------------------------------------------------------
__global__ void conv_f32_f16(const float* __restrict__ src,
                             _Float16* __restrict__ dst, int n4)
{
    int i = blockIdx.x * 256 + threadIdx.x;
    if (i >= n4) return;
    float4 v = ((const float4*)src)[i];
    f16x4 o;
    o[0] = (_Float16)v.x; o[1] = (_Float16)v.y;
    o[2] = (_Float16)v.z; o[3] = (_Float16)v.w;
    ((f16x4*)dst)[i] = o;
}

// Three W [512 x 512] (K x N) -> Wt [N x K] fp16, one kernel (blockIdx.z picks)
__global__ void transp3_f32_f16(const float* __restrict__ Wa,
                                const float* __restrict__ Wb,
                                const float* __restrict__ Wc,
                                _Float16* __restrict__ Ta,
                                _Float16* __restrict__ Tb,
                                _Float16* __restrict__ Tc)
{
    const float* W = (blockIdx.z == 0) ? Wa : (blockIdx.z == 1) ? Wb : Wc;
    _Float16*    T = (blockIdx.z == 0) ? Ta : (blockIdx.z == 1) ? Tb : Tc;
    __shared__ float t[32][33];
    int bx = blockIdx.x * 32, by = blockIdx.y * 32;
    int tx = threadIdx.x, ty = threadIdx.y;   // 32 x 8
    #pragma unroll
    for (int i = 0; i < 32; i += 8)
        t[ty + i][tx] = W[(size_t)(by + ty + i) * 512 + bx + tx];
    __syncthreads();
    #pragma unroll
    for (int i = 0; i < 32; i += 8)
        T[(size_t)(bx + ty + i) * 512 + by + tx] = (_Float16)t[tx][ty + i];
}

// ---------------------------------------------------------------------------
// fp16 MFMA GEMM: C[M,N] = A16[M,K] @ Bt16[N,K]^T (+bias)
// ---------------------------------------------------------------------------
__global__ __launch_bounds__(256) void gemm_f16_mfma(
    const _Float16* __restrict__ A16, const _Float16* __restrict__ Bt16,
    const float* __restrict__ bias, float* __restrict__ Cp,
    _Float16* __restrict__ C16, int M, int Nn, int K)
{
    __shared__ _Float16 As[128 * 32] __attribute__((aligned(16)));
    __shared__ _Float16 Bs[128 * 32] __attribute__((aligned(16)));
    const int tid  = threadIdx.x;
    const int wave = tid >> 6;
    const int lane = tid & 63;
    const int row0 = blockIdx.y * 128;
    const int col0 = blockIdx.x * 128;
    const int wy = wave >> 1, wx = wave & 1;

    const int lrow = lane >> 2;
    const int lk   = (lane & 3) * 8;

    f32x4 acc[4][4] = {};

    for (int k0 = 0; k0 < K; k0 += 32) {
        if (k0) __syncthreads();
        #pragma unroll
        for (int r = 0; r < 2; ++r) {
            const int chunk = r * 4 + wave;
            const int trow  = chunk * 16 + lrow;
            const _Float16* ga = A16 + (size_t)(row0 + trow) * K + k0 + lk;
            GLD_LDS16(ga, &As[chunk * 512]);
            const _Float16* gb = Bt16 + (size_t)(col0 + trow) * K + k0 + lk;
            GLD_LDS16(gb, &Bs[chunk * 512]);
        }
        __syncthreads();

        const int quad = lane >> 4;
        const int l16  = lane & 15;
        f16x8 af[4], bf[4];
        #pragma unroll
        for (int m = 0; m < 4; ++m)
            af[m] = *(const f16x8*)&As[(wy * 64 + m * 16 + l16) * 32 + quad * 8];
        #pragma unroll
        for (int n = 0; n < 4; ++n)
            bf[n] = *(const f16x8*)&Bs[(wx * 64 + n * 16 + l16) * 32 + quad * 8];
        #pragma unroll
        for (int m = 0; m < 4; ++m)
            #pragma unroll
            for (int n = 0; n < 4; ++n)
                acc[m][n] = __builtin_amdgcn_mfma_f32_16x16x32_f16(
                    af[m], bf[n], acc[m][n], 0, 0, 0);
    }

    const int quad = lane >> 4;
    const int l16  = lane & 15;
    #pragma unroll
    for (int m = 0; m < 4; ++m) {
        #pragma unroll
        for (int n = 0; n < 4; ++n) {
            const int col = col0 + wx * 64 + n * 16 + l16;
            const float bv = bias ? bias[col] : 0.0f;
            #pragma unroll
            for (int r = 0; r < 4; ++r) {
                const int row = row0 + wy * 64 + m * 16 + quad * 4 + r;
                if (row < M) {
                    float v = acc[m][n][r] + bv;
                    if (Cp)  Cp[(size_t)row * Nn + col] = v;
                    if (C16) C16[(size_t)row * Nn + col] = (_Float16)v;
                }
            }
        }
    }
}

// ---------------------------------------------------------------------------
// Tiled fp32 GEMM (layer 3, N=64)
// ---------------------------------------------------------------------------
__global__ __launch_bounds__(256) void gemm_bias_f32(
    const float* __restrict__ A, const float* __restrict__ B,
    const float* __restrict__ bias, float* __restrict__ Cm,
    int M, int Nn, int K)
{
    __shared__ float As[16][68];
    __shared__ float Bs[16][68];
    const int tid  = threadIdx.x;
    const int row0 = blockIdx.y * 64;
    const int col0 = blockIdx.x * 64;
    const int tx = tid & 15, ty = tid >> 4;
    const int am = tid >> 2,  ak = (tid & 3) << 2;
    const int bk = tid >> 4,  bc = (tid & 15) << 2;
    float acc[4][4] = {};
    for (int k0 = 0; k0 < K; k0 += 16) {
        float4 av;
        if (row0 + am < M)
            av = *(const float4*)(A + (size_t)(row0 + am) * K + k0 + ak);
        else
            av = make_float4(0.f, 0.f, 0.f, 0.f);
        As[ak + 0][am] = av.x; As[ak + 1][am] = av.y;
        As[ak + 2][am] = av.z; As[ak + 3][am] = av.w;
        float4 bv = *(const float4*)(B + (size_t)(k0 + bk) * Nn + col0 + bc);
        Bs[bk][bc + 0] = bv.x; Bs[bk][bc + 1] = bv.y;
        Bs[bk][bc + 2] = bv.z; Bs[bk][bc + 3] = bv.w;
        __syncthreads();
        #pragma unroll
        for (int kk = 0; kk < 16; ++kk) {
            float a0 = As[kk][ty * 4 + 0], a1 = As[kk][ty * 4 + 1];
            float a2 = As[kk][ty * 4 + 2], a3 = As[kk][ty * 4 + 3];
            float b0 = Bs[kk][tx * 4 + 0], b1 = Bs[kk][tx * 4 + 1];
            float b2 = Bs[kk][tx * 4 + 2], b3 = Bs[kk][tx * 4 + 3];
            acc[0][0] = fmaf(a0, b0, acc[0][0]); acc[0][1] = fmaf(a0, b1, acc[0][1]);
            acc[0][2] = fmaf(a0, b2, acc[0][2]); acc[0][3] = fmaf(a0, b3, acc[0][3]);
            acc[1][0] = fmaf(a1, b0, acc[1][0]); acc[1][1] = fmaf(a1, b1, acc[1][1]);
            acc[1][2] = fmaf(a1, b2, acc[1][2]); acc[1][3] = fmaf(a1, b3, acc[1][3]);
            acc[2][0] = fmaf(a2, b0, acc[2][0]); acc[2][1] = fmaf(a2, b1, acc[2][1]);
            acc[2][2] = fmaf(a2, b2, acc[2][2]); acc[2][3] = fmaf(a2, b3, acc[2][3]);
            acc[3][0] = fmaf(a3, b0, acc[3][0]); acc[3][1] = fmaf(a3, b1, acc[3][1]);
            acc[3][2] = fmaf(a3, b2, acc[3][2]); acc[3][3] = fmaf(a3, b3, acc[3][3]);
        }
        __syncthreads();
    }
    #pragma unroll
    for (int i = 0; i < 4; ++i) {
        int r = row0 + ty * 4 + i;
        if (r < M) {
            #pragma unroll
            for (int j = 0; j < 4; ++j) {
                int c = col0 + tx * 4 + j;
                float v = acc[i][j];
                if (bias) v += bias[c];
                Cm[(size_t)r * Nn + c] = v;
            }
        }
    }
}

// ---------------------------------------------------------------------------
// Scores, vectorized for NH=8 fp16: lane owns channels [8l,8l+8), head=l>>3.
// 4 nodes per 256-thr block (1 wave each, no barriers).
// ---------------------------------------------------------------------------
__global__ __launch_bounds__(256) void compute_scores8(
    const _Float16* __restrict__ Hf, const float* __restrict__ a_s,
    const float* __restrict__ a_d, float* __restrict__ ssrc,
    float* __restrict__ sdst)
{
    const int lane = threadIdx.x & 63;
    const int node = blockIdx.x * 4 + (threadIdx.x >> 6);
    const int head = lane >> 3;
    f16x8 hv = *(const f16x8*)(Hf + (size_t)node * HC + lane * 8);
    float vs = 0.f, vd = 0.f;
    #pragma unroll
    for (int c = 0; c < 8; ++c) {
        float v = (float)hv[c];
        vs = fmaf(v, a_s[lane * 8 + c], vs);
        vd = fmaf(v, a_d[lane * 8 + c], vd);
    }
    vs += __shfl_xor(vs, 1); vs += __shfl_xor(vs, 2); vs += __shfl_xor(vs, 4);
    vd += __shfl_xor(vd, 1); vd += __shfl_xor(vd, 2); vd += __shfl_xor(vd, 4);
    if ((lane & 7) == 0) {
        ssrc[node * HEADS8 + head] = vs;
        sdst[node * HEADS8 + head] = vd;
    }
}

// Generic scores (layer 3: NH=1, fp32)
template <int NH, typename TH>
__global__ __launch_bounds__(64) void compute_scores(
    const TH* __restrict__ Hf, const float* __restrict__ a_s,
    const float* __restrict__ a_d, float* __restrict__ ssrc,
    float* __restrict__ sdst)
{
    const int node = blockIdx.x;
    const int lane = threadIdx.x;
    const TH* hp = Hf + (size_t)node * (NH * 64) + lane;
    #pragma unroll
    for (int h = 0; h < NH; ++h) {
        float v  = (float)hp[h * 64];
        float vs = v * a_s[h * 64 + lane];
        float vd = v * a_d[h * 64 + lane];
        #pragma unroll
        for (int o = 32; o; o >>= 1) {
            vs += __shfl_down(vs, o);
            vd += __shfl_down(vd, o);
        }
        if (lane == 0) {
            ssrc[node * NH + h] = vs;
            sdst[node * NH + h] = vd;
        }
    }
}

// ---------------------------------------------------------------------------
// Segment-softmax aggregation, NH=8 fp16, VECTORIZED:
// lane owns channels [8l, 8l+8) (f16x8 gather = 1 dwordx4/edge), head = l>>3.
// alpha via LDS broadcast exL[j*8+head].
// ---------------------------------------------------------------------------
__global__ __launch_bounds__(64) void gat_aggregate8(
    const _Float16* __restrict__ Hf, const float* __restrict__ ssrc,
    const float* __restrict__ sdst, const int* __restrict__ off,
    const int* __restrict__ csr, const float* __restrict__ bias,
    float* __restrict__ out)
{
    const int n    = blockIdx.x;
    const int lane = threadIdx.x;
    const int head = lane >> 3;
    const int e0 = off[n], e1 = off[n + 1];

    float sd[8];
    #pragma unroll
    for (int h = 0; h < 8; ++h) sd[h] = sdst[n * 8 + h];

    // pass 1: per-head max
    float mx[8];
    #pragma unroll
    for (int h = 0; h < 8; ++h) mx[h] = -1e30f;
    for (int e = e0 + lane; e < e1; e += 64) {
        int s = csr[e];
        #pragma unroll
        for (int h = 0; h < 8; ++h) {
            float l = ssrc[s * 8 + h] + sd[h];
            l = (l > 0.f) ? l : 0.2f * l;
            mx[h] = fmaxf(mx[h], l);
        }
    }
    #pragma unroll
    for (int h = 0; h < 8; ++h)
        #pragma unroll
        for (int o = 1; o < 64; o <<= 1)
            mx[h] = fmaxf(mx[h], __shfl_xor(mx[h], o));

    // pass 2: exp + weighted accumulate (8 channels per lane)
    __shared__ float exL[64 * 8];
    __shared__ int   srcL[64];
    float acc[8]  = {};
    float ssum[8] = {};
    for (int base = e0; base < e1; base += 64) {
        int cnt = e1 - base; if (cnt > 64) cnt = 64;
        if (lane < cnt) {
            int s = csr[base + lane];
            srcL[lane] = s;
            #pragma unroll
            for (int h = 0; h < 8; ++h) {
                float l = ssrc[s * 8 + h] + sd[h];
                l = (l > 0.f) ? l : 0.2f * l;
                float ex = expf(l - mx[h]);
                exL[lane * 8 + h] = ex;
                ssum[h] += ex;
            }
        }
        __syncthreads();
        for (int j = 0; j < cnt; ++j) {
            const int s = srcL[j];
            f16x8 hv = *(const f16x8*)(Hf + (size_t)s * HC + lane * 8);
            const float al = exL[j * 8 + head];
            #pragma unroll
            for (int c = 0; c < 8; ++c)
                acc[c] = fmaf(al, (float)hv[c], acc[c]);
        }
        __syncthreads();
    }
    #pragma unroll
    for (int h = 0; h < 8; ++h)
        #pragma unroll
        for (int o = 1; o < 64; o <<= 1)
            ssum[h] += __shfl_xor(ssum[h], o);

    const float inv = 1.0f / (ssum[head] + 1e-16f);
    float* op = out + (size_t)n * HC + lane * 8;
    const float* bp = bias + lane * 8;
    #pragma unroll
    for (int c = 0; c < 8; ++c)
        op[c] = acc[c] * inv + bp[c];
}

// Generic aggregate (layer 3: NH=1, fp32; 1 channel/lane already optimal)
template <int NH, typename TH>
__global__ __launch_bounds__(64) void gat_aggregate(
    const TH* __restrict__ Hf, const float* __restrict__ ssrc,
    const float* __restrict__ sdst, const int* __restrict__ off,
    const int* __restrict__ csr, const float* __restrict__ bias,
    float* __restrict__ out)
{
    const int n    = blockIdx.x;
    const int lane = threadIdx.x;
    const int e0 = off[n], e1 = off[n + 1];

    float sd[NH];
    #pragma unroll
    for (int h = 0; h < NH; ++h) sd[h] = sdst[n * NH + h];

    float mx[NH];
    #pragma unroll
    for (int h = 0; h < NH; ++h) mx[h] = -1e30f;
    for (int e = e0 + lane; e < e1; e += 64) {
        int s = csr[e];
        #pragma unroll
        for (int h = 0; h < NH; ++h) {
            float l = ssrc[s * NH + h] + sd[h];
            l = (l > 0.f) ? l : 0.2f * l;
            mx[h] = fmaxf(mx[h], l);
        }
    }
    #pragma unroll
    for (int h = 0; h < NH; ++h)
        #pragma unroll
        for (int o = 1; o < 64; o <<= 1)
            mx[h] = fmaxf(mx[h], __shfl_xor(mx[h], o));

    __shared__ float exL[64][NH];
    __shared__ int   srcL[64];
    float acc[NH]  = {};
    float ssum[NH] = {};
    for (int base = e0; base < e1; base += 64) {
        int cnt = e1 - base; if (cnt > 64) cnt = 64;
        if (lane < cnt) {
            int s = csr[base + lane];
            srcL[lane] = s;
            #pragma unroll
            for (int h = 0; h < NH; ++h) {
                float l = ssrc[s * NH + h] + sd[h];
                l = (l > 0.f) ? l : 0.2f * l;
                float ex = expf(l - mx[h]);
                exL[lane][h] = ex;
                ssum[h] += ex;
            }
        }
        __syncthreads();
        for (int j = 0; j < cnt; ++j) {
            const int s = srcL[j];
            const TH* hp = Hf + (size_t)s * (NH * 64) + lane;
            #pragma unroll
            for (int h = 0; h < NH; ++h)
                acc[h] = fmaf(exL[j][h], (float)hp[h * 64], acc[h]);
        }
        __syncthreads();
    }
    #pragma unroll
    for (int h = 0; h < NH; ++h)
        #pragma unroll
        for (int o = 1; o < 64; o <<= 1)
            ssum[h] += __shfl_xor(ssum[h], o);

    #pragma unroll
    for (int h = 0; h < NH; ++h)
        out[(size_t)n * (NH * 64) + h * 64 + lane] =
            acc[h] / (ssum[h] + 1e-16f) + bias[h * 64 + lane];
}

// ---------------------------------------------------------------------------
// BatchNorm: partial column sums (no atomics), finalize reduces partials
// ---------------------------------------------------------------------------
__global__ void bn_stats_part(const float* __restrict__ x,
                              float* __restrict__ psum, float* __restrict__ psq,
                              int rows, int cols)
{
    const int c   = threadIdx.x;   // blockDim.x == cols
    const int blk = blockIdx.x;    // NPART blocks
    float s = 0.f, sq = 0.f;
    for (int r = blk; r < rows; r += NPART) {
        float v = x[(size_t)r * cols + c];
        s += v; sq += v * v;
    }
    psum[(size_t)blk * cols + c] = s;
    psq [(size_t)blk * cols + c] = sq;
}

__global__ void bn_finalize(const float* __restrict__ psum,
                            const float* __restrict__ psq,
                            float* __restrict__ mean, float* __restrict__ invstd,
                            int cols, float invN)
{
    int c = blockIdx.x * blockDim.x + threadIdx.x;
    if (c >= cols) return;
    float s = 0.f, sq = 0.f;
    for (int p = 0; p < NPART; ++p) {
        s  += psum[(size_t)p * cols + c];
        sq += psq [(size_t)p * cols + c];
    }
    float mu  = s * invN;
    float var = sq * invN - mu * mu;
    mean[c]   = mu;
    invstd[c] = 1.0f / sqrtf(var + 1e-5f);
}

// BN apply + ELU + residual; optionally emits fp16 copy for next fp16 GEMM
__global__ void bn_apply(float* __restrict__ x, const float* __restrict__ res,
                         const float* __restrict__ mean, const float* __restrict__ invstd,
                         const float* __restrict__ g, const float* __restrict__ be,
                         _Float16* __restrict__ out16,
                         size_t total, int colmask, int do_elu)
{
    size_t i = (size_t)blockIdx.x * blockDim.x + threadIdx.x;
    if (i >= total) return;
    int c = (int)(i & (size_t)colmask);
    float v = g[c] * (x[i] - mean[c]) * invstd[c] + be[c];
    if (do_elu) v = (v > 0.f) ? v : expm1f(v);
    if (res) v += res[i];
    x[i] = v;
    if (out16) out16[i] = (_Float16)v;
}

// ---------------------------------------------------------------------------
// Global mean pool (segment-based) + final linear
// ---------------------------------------------------------------------------
__global__ __launch_bounds__(256) void pool_mean(
    const float* __restrict__ x, const int* __restrict__ goff,
    float* __restrict__ means)
{
    const int g    = blockIdx.x;
    const int lane = threadIdx.x & 63;   // channel
    const int wave = threadIdx.x >> 6;   // 0..3
    const int r0 = goff[g], r1 = goff[g + 1];
    float s = 0.f;
    for (int r = r0 + wave; r < r1; r += 4)
        s += x[(size_t)r * CH + lane];
    __shared__ float red[4][CH];
    red[wave][lane] = s;
    __syncthreads();
    if (wave == 0) {
        float tot = red[0][lane] + red[1][lane] + red[2][lane] + red[3][lane];
        float cnt = (float)(r1 - r0);
        means[g * CH + lane] = tot / fmaxf(cnt, 1.0f);
    }
}

__global__ __launch_bounds__(64) void final_linear(
    const float* __restrict__ means, const float* __restrict__ W,
    const float* __restrict__ b, float* __restrict__ out)
{
    const int g = blockIdx.x;
    const int j = threadIdx.x;
    float acc = b[j];
    for (int c = 0; c < CH; ++c)
        acc = fmaf(means[g * CH + c], W[c * NCLS + j], acc);
    out[g * NCLS + j] = acc;
}

// ---------------------------------------------------------------------------
// Host launcher
// ---------------------------------------------------------------------------
extern "C" void kernel_launch(void* const* d_in, const int* in_sizes, int n_in,
                              void* d_out, int out_size, void* d_ws, size_t ws_size,
                              hipStream_t stream)
{
    const float* x_in  = (const float*)d_in[0];
    const int*   ei    = (const int*)  d_in[1];
    const int*   batch = (const int*)  d_in[2];
    const float* enc_W = (const float*)d_in[3];
    const float* enc_b = (const float*)d_in[4];
    const float* W1  = (const float*)d_in[5];
    const float* as1 = (const float*)d_in[6];
    const float* ad1 = (const float*)d_in[7];
    const float* b1  = (const float*)d_in[8];
    const float* g1  = (const float*)d_in[9];
    const float* be1 = (const float*)d_in[10];
    const float* W2  = (const float*)d_in[11];
    const float* as2 = (const float*)d_in[12];
    const float* ad2 = (const float*)d_in[13];
    const float* b2  = (const float*)d_in[14];
    const float* g2  = (const float*)d_in[15];
    const float* be2 = (const float*)d_in[16];
    const float* W3  = (const float*)d_in[17];
    const float* as3 = (const float*)d_in[18];
    const float* ad3 = (const float*)d_in[19];
    const float* b3  = (const float*)d_in[20];
    const float* g3  = (const float*)d_in[21];
    const float* be3 = (const float*)d_in[22];
    const float* linW = (const float*)d_in[23];
    const float* linb = (const float*)d_in[24];
    float* out = (float*)d_out;

    char* ws = (char*)d_ws;
    size_t off_b = 0;
    auto alloc = [&](size_t bytes) -> void* {
        void* p = ws + off_b;
        off_b = (off_b + bytes + 255) & ~(size_t)255;
        return p;
    };
    float*    xA     = (float*)alloc((size_t)NNODES * HC * 4);
    float*    xC     = (float*)alloc((size_t)NNODES * HC * 4);
    _Float16* f16A   = (_Float16*)alloc((size_t)MPAD * HC * 2);
    _Float16* f16B   = (_Float16*)alloc((size_t)MPAD * HC * 2);
    _Float16* H16    = (_Float16*)alloc((size_t)NNODES * HC * 2);
    float*    h3f    = (float*)alloc((size_t)NNODES * CH * 4);
    float*    g3o    = (float*)alloc((size_t)NNODES * CH * 4);
    _Float16* encWt  = (_Float16*)alloc((size_t)HC * FIN * 2);
    _Float16* W1t    = (_Float16*)alloc((size_t)HC * HC * 2);
    _Float16* W2t    = (_Float16*)alloc((size_t)HC * HC * 2);
    float* ssrc   = (float*)alloc((size_t)NNODES * HEADS8 * 4);
    float* sdst   = (float*)alloc((size_t)NNODES * HEADS8 * 4);
    int*   deg    = (int*)  alloc((size_t)NNODES * 4);
    int*   offp   = (int*)  alloc((size_t)(NNODES + 1) * 4);
    int*   cursor = (int*)  alloc((size_t)NNODES * 4);
    int*   csr    = (int*)  alloc((size_t)EPLUS * 4);
    int*   goff   = (int*)  alloc((size_t)(NG + 1) * 4);
    float* psum   = (float*)alloc((size_t)NPART * HC * 4);
    float* psq    = (float*)alloc((size_t)NPART * HC * 4);
    float* meanb  = (float*)alloc(HC * 4);
    float* invstd = (float*)alloc(HC * 4);
    float* gmeans = (float*)alloc((size_t)NG * CH * 4);

    // ---- CSR build + graph offsets (goff fused into count)
    hipMemsetAsync(deg, 0, (size_t)NNODES * 4, stream);
    count_deg_goff<<<(EPLUS + 255) / 256, 256, 0, stream>>>(ei, deg, batch, goff);
    exscan_deg<<<1, 256, 0, stream>>>(deg, offp, cursor);
    scatter_edges<<<(EPLUS + 255) / 256, 256, 0, stream>>>(ei, cursor, csr);

    // ---- fp16 conversions (input + 3 transposed weights in one kernel)
    {
        int n4 = NNODES * FIN / 4;
        conv_f32_f16<<<(n4 + 255) / 256, 256, 0, stream>>>(x_in, f16A, n4);
        dim3 tg(16, 16, 3), tb(32, 8);
        transp3_f32_f16<<<tg, tb, 0, stream>>>(enc_W, W1, W2, encWt, W1t, W2t);
    }

    const dim3 mfma_grid(HC / 128, MPAD / 128);
    const dim3 gemm_grid_c(CH / 64, (NNODES + 63) / 64);

    // ---- Encoder
    gemm_f16_mfma<<<mfma_grid, 256, 0, stream>>>(f16A, encWt, enc_b, xA, f16B,
                                                 NNODES, HC, FIN);

    // ---- GAT layer (fp16 H path, vectorized scores/aggregate)
    auto run_layer = [&](const _Float16* a16, const _Float16* wt,
                         const float* xin_res, float* gout, _Float16* out16,
                         const float* a_s, const float* a_d,
                         const float* bconv, const float* gg, const float* bb) {
        gemm_f16_mfma<<<mfma_grid, 256, 0, stream>>>(a16, wt, nullptr, nullptr,
                                                     H16, NNODES, HC, HC);
        compute_scores8<<<NNODES / 4, 256, 0, stream>>>(H16, a_s, a_d, ssrc, sdst);
        gat_aggregate8<<<NNODES, 64, 0, stream>>>(H16, ssrc, sdst, offp, csr,
                                                  bconv, gout);
        bn_stats_part<<<NPART, HC, 0, stream>>>(gout, psum, psq, NNODES, HC);
        bn_finalize<<<1, HC, 0, stream>>>(psum, psq, meanb, invstd, HC,
                                          1.0f / NNODES);
        size_t total = (size_t)NNODES * HC;
        bn_apply<<<(total + 255) / 256, 256, 0, stream>>>(
            gout, xin_res, meanb, invstd, gg, bb, out16, total, HC - 1, 1);
    };

    run_layer(f16B, W1t, xA, xC, f16A, as1, ad1, b1, g1, be1);
    run_layer(f16A, W2t, xC, xA, nullptr, as2, ad2, b2, g2, be2);

    // ---- Layer 3 (heads=1, C=64, fp32 GEMM)
    gemm_bias_f32<<<gemm_grid_c, 256, 0, stream>>>(xA, W3, nullptr, h3f,
                                                   NNODES, CH, HC);
    compute_scores<1, float><<<NNODES, 64, 0, stream>>>(h3f, as3, ad3, ssrc, sdst);
    gat_aggregate<1, float><<<NNODES, 64, 0, stream>>>(h3f, ssrc, sdst, offp,
                                                       csr, b3, g3o);
    bn_stats_part<<<NPART, CH, 0, stream>>>(g3o, psum, psq, NNODES, CH);
    bn_finalize<<<1, CH, 0, stream>>>(psum, psq, meanb, invstd, CH,
                                      1.0f / NNODES);
    {
        size_t total = (size_t)NNODES * CH;
        bn_apply<<<(total + 255) / 256, 256, 0, stream>>>(
            g3o, nullptr, meanb, invstd, g3, be3, nullptr, total, CH - 1, 0);
    }

    // ---- Global mean pool + final linear
    pool_mean<<<NG, 256, 0, stream>>>(g3o, goff, gmeans);
    final_linear<<<NG, 64, 0, stream>>>(gmeans, linW, linb, out);
}